// Round 10
// baseline (734.312 us; speedup 1.0000x reference)
//
#include <hip/hip_runtime.h>

// Problem dims (fixed)
constexpr int T  = 512;
constexpr int NB = 64;    // batch
constexpr int NI = 128;   // input
constexpr int NH = 512;   // hidden
constexpr int NO = 64;    // output

constexpr float ALPHA = 0.2f;
constexpr float NSC   = 0.063245553203367586f; // 0.1*sqrt(2*ALPHA)

typedef _Float16 h2_t __attribute__((ext_vector_type(2)));

#if defined(__has_builtin)
#  if __has_builtin(__builtin_amdgcn_fdot2)
#    define HAS_FDOT2 1
#  endif
#endif
#ifndef HAS_FDOT2
#  define HAS_FDOT2 0
#endif

// acc += dot(two f16 pairs)  — v_dot2_f32_f16 when available
__device__ __forceinline__ float dot2(uint32_t wbits, uint32_t hbits, float acc) {
#if HAS_FDOT2
    return __builtin_amdgcn_fdot2(__builtin_bit_cast(h2_t, wbits),
                                  __builtin_bit_cast(h2_t, hbits), acc, false);
#else
    const h2_t wv = __builtin_bit_cast(h2_t, wbits);
    const h2_t hv = __builtin_bit_cast(h2_t, hbits);
    return acc + (float)wv.x * (float)hv.x + (float)wv.y * (float)hv.y;
#endif
}

__device__ __forceinline__ uint32_t pk2(float x, float y) {
    return __builtin_bit_cast(uint32_t, (h2_t){(_Float16)x, (_Float16)y});
}

// ---------------------------------------------------------------------------
// Generic fp32 GEMM: C[M,N] = A[M,K] @ B[N,K]^T + bias[N]   (R3-proven)
__global__ __launch_bounds__(256) void k_gemm_nt_bias(
    const float* __restrict__ A, const float* __restrict__ Bm,
    const float* __restrict__ bias, float* __restrict__ C,
    int M, int N, int K)
{
    __shared__ __align__(16) float As[32][68];
    __shared__ __align__(16) float Bs[32][68];
    const int tid = threadIdx.x;
    const int tx = tid & 15, ty = tid >> 4;
    const long row0 = (long)blockIdx.x * 64;
    const long col0 = (long)blockIdx.y * 64;
    const int lr = tid >> 3;
    const int lq = tid & 7;

    float acc[4][4] = {};

    for (int kt = 0; kt < K; kt += 32) {
        #pragma unroll
        for (int hh = 0; hh < 2; ++hh) {
            const int r = lr + hh * 32;
            const float4 va = *(const float4*)&A[(size_t)(row0 + r) * K + kt + lq * 4];
            As[lq*4+0][r] = va.x; As[lq*4+1][r] = va.y;
            As[lq*4+2][r] = va.z; As[lq*4+3][r] = va.w;
            const float4 vb = *(const float4*)&Bm[(size_t)(col0 + r) * K + kt + lq * 4];
            Bs[lq*4+0][r] = vb.x; Bs[lq*4+1][r] = vb.y;
            Bs[lq*4+2][r] = vb.z; Bs[lq*4+3][r] = vb.w;
        }
        __syncthreads();
        #pragma unroll
        for (int kk = 0; kk < 32; ++kk) {
            const float4 a4 = *(const float4*)&As[kk][ty * 4];
            const float4 b4 = *(const float4*)&Bs[kk][tx * 4];
            const float a[4] = {a4.x, a4.y, a4.z, a4.w};
            const float b[4] = {b4.x, b4.y, b4.z, b4.w};
            #pragma unroll
            for (int i = 0; i < 4; ++i)
                #pragma unroll
                for (int j = 0; j < 4; ++j)
                    acc[i][j] += a[i] * b[j];
        }
        __syncthreads();
    }

    #pragma unroll
    for (int i = 0; i < 4; ++i) {
        const long r = row0 + ty * 4 + i;
        const int  cc = (int)col0 + tx * 4;
        float4 ov;
        ov.x = acc[i][0] + bias[cc + 0];
        ov.y = acc[i][1] + bias[cc + 1];
        ov.z = acc[i][2] + bias[cc + 2];
        ov.w = acc[i][3] + bias[cc + 3];
        *(float4*)&C[(size_t)r * N + cc] = ov;
    }
}

// ---------------------------------------------------------------------------
// u32 exchange word: [31:16]=f16(h), [15:0]=tag.  R3-proven RMW protocol.
__device__ __forceinline__ uint32_t pack_h(float h, uint32_t tag) {
    const _Float16 hf = (_Float16)h;                    // RNE f32->f16
    const uint32_t hb = __builtin_bit_cast(unsigned short, hf);
    return (hb << 16) | (tag & 0xFFFFu);
}

// ---------------------------------------------------------------------------
// Recurrent kernel = R9 with W held in 64 NAMED SCALAR u32 registers.
//  R9's VGPR_Count=48 proved the wp0[32]/wp1[32] ARRAYS were allocated to
//  scratch (rule #20: aggregate defeated SROA; asm pinned values, not the
//  array). Named scalars + fully static macro-unrolled load/dot leave the
//  allocator no memory object — registers or nothing; pins block remat.
// Everything else identical to R9 (passed, absmax 0.0156):
//  256 WGs = 64 groups (1 batch) x 4 members; member m owns cols
//  [128m,128m+128); wave w owns k-chunk [64w,64w+64); lane l -> cols
//  {l, l+64}; h f16 in LDS (8 wave-uniform b128 reads/thread);
//  u32 RMW tagged sync, 2-slot parity, budgeted spin.
__global__ __launch_bounds__(512, 2) void k_rnn(
    const float* __restrict__ W_rec,   // [H][H]
    const float* __restrict__ noise,   // [T][B][H]
    float* __restrict__ rnn,           // [T][B][H]: xin+b_rec in, h out
    uint32_t* __restrict__ ex)         // [2][B][H] tagged words
{
    const int bid = blockIdx.x;
    const int g = bid & 63;        // group == batch
    const int m = bid >> 6;        // member 0..3
    const int tid = threadIdx.x;
    const int w = tid >> 6;        // wave = k-chunk (64 k wide)
    const int l = tid & 63;        // lane -> cols {l, l+64} of slice

    __shared__ __align__(16) unsigned short hbf[NH];  // f16 h (1 KB)
    __shared__ __align__(16) float pr[8][128];        // per-chunk partials

    // ---- 64 named W scalars (2 cols x 32 packed-f16 words) ----
    uint32_t wa0,wa1,wa2,wa3,wa4,wa5,wa6,wa7,wa8,wa9,wa10,wa11,wa12,wa13,wa14,wa15,
             wa16,wa17,wa18,wa19,wa20,wa21,wa22,wa23,wa24,wa25,wa26,wa27,wa28,wa29,wa30,wa31;
    uint32_t wb0,wb1,wb2,wb3,wb4,wb5,wb6,wb7,wb8,wb9,wb10,wb11,wb12,wb13,wb14,wb15,
             wb16,wb17,wb18,wb19,wb20,wb21,wb22,wb23,wb24,wb25,wb26,wb27,wb28,wb29,wb30,wb31;
    {
        const float* p0 = W_rec + (size_t)(m * 128 + l) * NH + w * 64;
        const float* p1 = W_rec + (size_t)(m * 128 + l + 64) * NH + w * 64;
#define LDW(P, VA, VB, OFF) { const float4 q_ = *(const float4*)((P) + (OFF)); \
                              VA = pk2(q_.x, q_.y); VB = pk2(q_.z, q_.w); }
        LDW(p0, wa0,  wa1,   0) LDW(p0, wa2,  wa3,   4)
        LDW(p0, wa4,  wa5,   8) LDW(p0, wa6,  wa7,  12)
        LDW(p0, wa8,  wa9,  16) LDW(p0, wa10, wa11, 20)
        LDW(p0, wa12, wa13, 24) LDW(p0, wa14, wa15, 28)
        LDW(p0, wa16, wa17, 32) LDW(p0, wa18, wa19, 36)
        LDW(p0, wa20, wa21, 40) LDW(p0, wa22, wa23, 44)
        LDW(p0, wa24, wa25, 48) LDW(p0, wa26, wa27, 52)
        LDW(p0, wa28, wa29, 56) LDW(p0, wa30, wa31, 60)
        LDW(p1, wb0,  wb1,   0) LDW(p1, wb2,  wb3,   4)
        LDW(p1, wb4,  wb5,   8) LDW(p1, wb6,  wb7,  12)
        LDW(p1, wb8,  wb9,  16) LDW(p1, wb10, wb11, 20)
        LDW(p1, wb12, wb13, 24) LDW(p1, wb14, wb15, 28)
        LDW(p1, wb16, wb17, 32) LDW(p1, wb18, wb19, 36)
        LDW(p1, wb20, wb21, 40) LDW(p1, wb22, wb23, 44)
        LDW(p1, wb24, wb25, 48) LDW(p1, wb26, wb27, 52)
        LDW(p1, wb28, wb29, 56) LDW(p1, wb30, wb31, 60)
#undef LDW
    }
#define PIN8(A,B,C,D,E,F,G,H) asm volatile("" : "+v"(A),"+v"(B),"+v"(C),"+v"(D),"+v"(E),"+v"(F),"+v"(G),"+v"(H));
    PIN8(wa0,wa1,wa2,wa3,wa4,wa5,wa6,wa7)
    PIN8(wa8,wa9,wa10,wa11,wa12,wa13,wa14,wa15)
    PIN8(wa16,wa17,wa18,wa19,wa20,wa21,wa22,wa23)
    PIN8(wa24,wa25,wa26,wa27,wa28,wa29,wa30,wa31)
    PIN8(wb0,wb1,wb2,wb3,wb4,wb5,wb6,wb7)
    PIN8(wb8,wb9,wb10,wb11,wb12,wb13,wb14,wb15)
    PIN8(wb16,wb17,wb18,wb19,wb20,wb21,wb22,wb23)
    PIN8(wb24,wb25,wb26,wb27,wb28,wb29,wb30,wb31)
#undef PIN8

    const int gc = m * 128 + tid;            // epilogue col (tid<128)

    // poller mapping (tid>=128): one u32 word of one peer
    const int q    = tid - 128;              // 0..383
    const int pp   = q >> 7;                 // 0..2
    const int pm   = pp + (pp >= m ? 1 : 0); // peer member
    const int pcol = pm * 128 + (q & 127);

    // zero f16 h
    hbf[tid] = 0;

    // fp32 h_old carried in registers (epilogue threads only)
    float hreg = 0.f;

    // prefetch t=0 xin(+b_rec)/noise
    float xin_pf = 0.f, noi_pf = 0.f;
    if (tid < 128) {
        xin_pf = rnn[(size_t)g * NH + gc];
        noi_pf = noise[(size_t)g * NH + gc];
    }
    __syncthreads();

    int alive  = 1;
    int budget = 1 << 16;   // launch-global spin budget (hang-proof)

    for (int t = 0; t < T; ++t) {
        // ---- dot: cols {l, l+64}, k in [64w,64w+64), f16 LDS + fdot2 ----
        float aA0 = 0.f, aA1 = 0.f, aB0 = 0.f, aB1 = 0.f;
        {
            const uint4* hp = (const uint4*)&hbf[w * 64];  // 8 x (8 f16)
#define DOTB(N, A0, A1, A2, A3) { const uint4 u_ = hp[N]; \
            aA0 = dot2(wa##A0, u_.x, aA0); aA1 = dot2(wa##A1, u_.y, aA1); \
            aA0 = dot2(wa##A2, u_.z, aA0); aA1 = dot2(wa##A3, u_.w, aA1); \
            aB0 = dot2(wb##A0, u_.x, aB0); aB1 = dot2(wb##A1, u_.y, aB1); \
            aB0 = dot2(wb##A2, u_.z, aB0); aB1 = dot2(wb##A3, u_.w, aB1); }
            DOTB(0,  0,  1,  2,  3)
            DOTB(1,  4,  5,  6,  7)
            DOTB(2,  8,  9, 10, 11)
            DOTB(3, 12, 13, 14, 15)
            DOTB(4, 16, 17, 18, 19)
            DOTB(5, 20, 21, 22, 23)
            DOTB(6, 24, 25, 26, 27)
            DOTB(7, 28, 29, 30, 31)
#undef DOTB
        }
        pr[w][l]      = aA0 + aA1;
        pr[w][l + 64] = aB0 + aB1;
        __syncthreads();

        const uint32_t want = (uint32_t)(t + 1);
        uint32_t* slot = ex + (size_t)(t & 1) * NB * NH;

        if (tid < 128) {
            // ---- epilogue: reduce 8 chunk-partials, update, publish ----
            float sum = 0.f;
            #pragma unroll
            for (int k = 0; k < 8; ++k) sum += pr[k][tid];
            const float hn = fmaxf(xin_pf + sum, 0.f);     // b_rec folded in xin
            const float nw = (1.f - ALPHA) * hreg + ALPHA * hn + NSC * noi_pf;
            hreg = nw;
            const uint32_t pk = pack_h(nw, want);
            (void)__hip_atomic_exchange(&slot[(size_t)g * NH + gc], pk,
                                        __ATOMIC_RELAXED, __HIP_MEMORY_SCOPE_AGENT);
            hbf[gc] = (unsigned short)(pk >> 16);          // own col, same rounding
            rnn[((size_t)t * NB + g) * NH + gc] = nw;
            const int tn = (t + 1 < T) ? (t + 1) : t;
            xin_pf = rnn[((size_t)tn * NB + g) * NH + gc];
            noi_pf = noise[((size_t)tn * NB + g) * NH + gc];
        } else {
            // ---- gather: poll one peer word via RMW ----
            uint32_t v;
            if (alive) {
                for (;;) {
                    v = __hip_atomic_fetch_or(&slot[(size_t)g * NH + pcol], 0u,
                                              __ATOMIC_RELAXED, __HIP_MEMORY_SCOPE_AGENT);
                    if ((v & 0xFFFFu) == (want & 0xFFFFu)) break;
                    __builtin_amdgcn_s_sleep(1);
                    if (--budget < 0) { alive = 0; break; }   // fail loudly
                }
            } else {
                v = __hip_atomic_fetch_or(&slot[(size_t)g * NH + pcol], 0u,
                                          __ATOMIC_RELAXED, __HIP_MEMORY_SCOPE_AGENT);
            }
            hbf[pcol] = (unsigned short)(v >> 16);
        }
        __syncthreads();
    }
}

// ---------------------------------------------------------------------------
extern "C" void kernel_launch(void* const* d_in, const int* in_sizes, int n_in,
                              void* d_out, int out_size, void* d_ws, size_t ws_size,
                              hipStream_t stream)
{
    (void)in_sizes; (void)n_in; (void)out_size; (void)ws_size;
    const float* x     = (const float*)d_in[0];
    const float* noise = (const float*)d_in[1];
    const float* W_in  = (const float*)d_in[2];
    const float* W_rec = (const float*)d_in[3];
    const float* b_rec = (const float*)d_in[4];
    const float* W_out = (const float*)d_in[5];
    const float* b_out = (const float*)d_in[6];

    float* out = (float*)d_out;                       // [T*B][O]
    float* rnn = out + (size_t)T * NB * NO;           // [T*B][H] (second output)

    uint32_t* ex = (uint32_t*)d_ws;                   // [2][B][H] = 256 KB

    // clear exchange tags (replay-deterministic; tag 0 never polled-for)
    hipMemsetAsync(ex, 0, (size_t)2 * NB * NH * sizeof(uint32_t), stream);

    // xin = x @ W_in^T + b_rec  -> written into rnn region (in-place consumed)
    hipLaunchKernelGGL(k_gemm_nt_bias, dim3((T * NB) / 64, NH / 64), dim3(256), 0, stream,
                       x, W_in, b_rec, rnn, T * NB, NH, NI);

    // sequential recurrence: 256 WGs, named-scalar W, f16 fdot2, u32 RMW sync
    hipLaunchKernelGGL(k_rnn, dim3(256), dim3(512), 0, stream,
                       W_rec, noise, rnn, ex);

    // output = rnn @ W_out^T + b_out
    hipLaunchKernelGGL(k_gemm_nt_bias, dim3((T * NB) / 64, NO / 64), dim3(256), 0, stream,
                       rnn, W_out, b_out, out, T * NB, NO, NH);
}

// Round 12
// 718.243 us; speedup vs baseline: 1.0224x; 1.0224x over previous
//
#include <hip/hip_runtime.h>

// Problem dims (fixed)
constexpr int T  = 512;
constexpr int NB = 64;    // batch
constexpr int NI = 128;   // input
constexpr int NH = 512;   // hidden
constexpr int NO = 64;    // output

constexpr float ALPHA = 0.2f;
constexpr float NSC   = 0.063245553203367586f; // 0.1*sqrt(2*ALPHA)

typedef _Float16 h2_t __attribute__((ext_vector_type(2)));

#if defined(__has_builtin)
#  if __has_builtin(__builtin_amdgcn_fdot2)
#    define HAS_FDOT2 1
#  endif
#endif
#ifndef HAS_FDOT2
#  define HAS_FDOT2 0
#endif

// acc += dot(two f16 pairs)  — v_dot2_f32_f16 when available
__device__ __forceinline__ float dot2(uint32_t wbits, uint32_t hbits, float acc) {
#if HAS_FDOT2
    return __builtin_amdgcn_fdot2(__builtin_bit_cast(h2_t, wbits),
                                  __builtin_bit_cast(h2_t, hbits), acc, false);
#else
    const h2_t wv = __builtin_bit_cast(h2_t, wbits);
    const h2_t hv = __builtin_bit_cast(h2_t, hbits);
    return acc + (float)wv.x * (float)hv.x + (float)wv.y * (float)hv.y;
#endif
}

__device__ __forceinline__ uint32_t pk2(float x, float y) {
    return __builtin_bit_cast(uint32_t, (h2_t){(_Float16)x, (_Float16)y});
}

// ---------------------------------------------------------------------------
// Generic fp32 GEMM: C[M,N] = A[M,K] @ B[N,K]^T + bias[N]   (R3-proven)
__global__ __launch_bounds__(256) void k_gemm_nt_bias(
    const float* __restrict__ A, const float* __restrict__ Bm,
    const float* __restrict__ bias, float* __restrict__ C,
    int M, int N, int K)
{
    __shared__ __align__(16) float As[32][68];
    __shared__ __align__(16) float Bs[32][68];
    const int tid = threadIdx.x;
    const int tx = tid & 15, ty = tid >> 4;
    const long row0 = (long)blockIdx.x * 64;
    const long col0 = (long)blockIdx.y * 64;
    const int lr = tid >> 3;
    const int lq = tid & 7;

    float acc[4][4] = {};

    for (int kt = 0; kt < K; kt += 32) {
        #pragma unroll
        for (int hh = 0; hh < 2; ++hh) {
            const int r = lr + hh * 32;
            const float4 va = *(const float4*)&A[(size_t)(row0 + r) * K + kt + lq * 4];
            As[lq*4+0][r] = va.x; As[lq*4+1][r] = va.y;
            As[lq*4+2][r] = va.z; As[lq*4+3][r] = va.w;
            const float4 vb = *(const float4*)&Bm[(size_t)(col0 + r) * K + kt + lq * 4];
            Bs[lq*4+0][r] = vb.x; Bs[lq*4+1][r] = vb.y;
            Bs[lq*4+2][r] = vb.z; Bs[lq*4+3][r] = vb.w;
        }
        __syncthreads();
        #pragma unroll
        for (int kk = 0; kk < 32; ++kk) {
            const float4 a4 = *(const float4*)&As[kk][ty * 4];
            const float4 b4 = *(const float4*)&Bs[kk][tx * 4];
            const float a[4] = {a4.x, a4.y, a4.z, a4.w};
            const float b[4] = {b4.x, b4.y, b4.z, b4.w};
            #pragma unroll
            for (int i = 0; i < 4; ++i)
                #pragma unroll
                for (int j = 0; j < 4; ++j)
                    acc[i][j] += a[i] * b[j];
        }
        __syncthreads();
    }

    #pragma unroll
    for (int i = 0; i < 4; ++i) {
        const long r = row0 + ty * 4 + i;
        const int  cc = (int)col0 + tx * 4;
        float4 ov;
        ov.x = acc[i][0] + bias[cc + 0];
        ov.y = acc[i][1] + bias[cc + 1];
        ov.z = acc[i][2] + bias[cc + 2];
        ov.w = acc[i][3] + bias[cc + 3];
        *(float4*)&C[(size_t)r * N + cc] = ov;
    }
}

// ---------------------------------------------------------------------------
// u32 exchange word: [31:16]=f16(h), [15:0]=tag.  R3-proven RMW protocol.
__device__ __forceinline__ uint32_t pack_h(float h, uint32_t tag) {
    const _Float16 hf = (_Float16)h;                    // RNE f32->f16
    const uint32_t hb = __builtin_bit_cast(unsigned short, hf);
    return (hb << 16) | (tag & 0xFFFFu);
}

// ---------------------------------------------------------------------------
// Recurrent kernel = R10 body + amdgpu_waves_per_eu(2,2)  (the R12 fix).
//  Root cause of 4 rounds of W-spilling: __launch_bounds__(512,2) only sets
//  the MINIMUM waves/EU; LLVM's default range still TARGETS 8 waves/EU
//  (<=64 VGPRs), so the allocator spilled the 64 W words no matter how they
//  were expressed (R7 remat / R8 scratch / R9-R10 scratch-or-AGPR-spill,
//  VGPR_Count 48-108, all << the 114 live regs that 2-wave occupancy allows).
//  Grid = 256 = 1 WG/CU => real occupancy IS 2 waves/SIMD; pinning
//  waves_per_eu(2,2) makes the register budget exactly 256 and removes all
//  spill incentive. (R11's hard-coded AGPRs collided with the compiler's
//  own AGPR spill slots -> NaN; reverted.)
// Body identical to R10 (passed, absmax 0.0156): 256 WGs = 64 groups x 4
//  members; member m owns cols [128m,128m+128); wave w owns k-chunk
//  [64w,64w+64); lane l -> cols {l, l+64}; h f16 in LDS (8 wave-uniform
//  b128 reads/thread); named-scalar packed-f16 W + fdot2; u32 RMW tagged
//  sync, 2-slot parity, budgeted spin (hang-proof).
__global__
__attribute__((amdgpu_flat_work_group_size(512, 512)))
__attribute__((amdgpu_waves_per_eu(2, 2)))
void k_rnn(
    const float* __restrict__ W_rec,   // [H][H]
    const float* __restrict__ noise,   // [T][B][H]
    float* __restrict__ rnn,           // [T][B][H]: xin+b_rec in, h out
    uint32_t* __restrict__ ex)         // [2][B][H] tagged words
{
    const int bid = blockIdx.x;
    const int g = bid & 63;        // group == batch
    const int m = bid >> 6;        // member 0..3
    const int tid = threadIdx.x;
    const int w = tid >> 6;        // wave = k-chunk (64 k wide)
    const int l = tid & 63;        // lane -> cols {l, l+64} of slice

    __shared__ __align__(16) unsigned short hbf[NH];  // f16 h (1 KB)
    __shared__ __align__(16) float pr[8][128];        // per-chunk partials

    // ---- 64 named W scalars (2 cols x 32 packed-f16 words) ----
    uint32_t wa0,wa1,wa2,wa3,wa4,wa5,wa6,wa7,wa8,wa9,wa10,wa11,wa12,wa13,wa14,wa15,
             wa16,wa17,wa18,wa19,wa20,wa21,wa22,wa23,wa24,wa25,wa26,wa27,wa28,wa29,wa30,wa31;
    uint32_t wb0,wb1,wb2,wb3,wb4,wb5,wb6,wb7,wb8,wb9,wb10,wb11,wb12,wb13,wb14,wb15,
             wb16,wb17,wb18,wb19,wb20,wb21,wb22,wb23,wb24,wb25,wb26,wb27,wb28,wb29,wb30,wb31;
    {
        const float* p0 = W_rec + (size_t)(m * 128 + l) * NH + w * 64;
        const float* p1 = W_rec + (size_t)(m * 128 + l + 64) * NH + w * 64;
#define LDW(P, VA, VB, OFF) { const float4 q_ = *(const float4*)((P) + (OFF)); \
                              VA = pk2(q_.x, q_.y); VB = pk2(q_.z, q_.w); }
        LDW(p0, wa0,  wa1,   0) LDW(p0, wa2,  wa3,   4)
        LDW(p0, wa4,  wa5,   8) LDW(p0, wa6,  wa7,  12)
        LDW(p0, wa8,  wa9,  16) LDW(p0, wa10, wa11, 20)
        LDW(p0, wa12, wa13, 24) LDW(p0, wa14, wa15, 28)
        LDW(p0, wa16, wa17, 32) LDW(p0, wa18, wa19, 36)
        LDW(p0, wa20, wa21, 40) LDW(p0, wa22, wa23, 44)
        LDW(p0, wa24, wa25, 48) LDW(p0, wa26, wa27, 52)
        LDW(p0, wa28, wa29, 56) LDW(p0, wa30, wa31, 60)
        LDW(p1, wb0,  wb1,   0) LDW(p1, wb2,  wb3,   4)
        LDW(p1, wb4,  wb5,   8) LDW(p1, wb6,  wb7,  12)
        LDW(p1, wb8,  wb9,  16) LDW(p1, wb10, wb11, 20)
        LDW(p1, wb12, wb13, 24) LDW(p1, wb14, wb15, 28)
        LDW(p1, wb16, wb17, 32) LDW(p1, wb18, wb19, 36)
        LDW(p1, wb20, wb21, 40) LDW(p1, wb22, wb23, 44)
        LDW(p1, wb24, wb25, 48) LDW(p1, wb26, wb27, 52)
        LDW(p1, wb28, wb29, 56) LDW(p1, wb30, wb31, 60)
#undef LDW
    }
#define PIN8(A,B,C,D,E,F,G,H) asm volatile("" : "+v"(A),"+v"(B),"+v"(C),"+v"(D),"+v"(E),"+v"(F),"+v"(G),"+v"(H));
    PIN8(wa0,wa1,wa2,wa3,wa4,wa5,wa6,wa7)
    PIN8(wa8,wa9,wa10,wa11,wa12,wa13,wa14,wa15)
    PIN8(wa16,wa17,wa18,wa19,wa20,wa21,wa22,wa23)
    PIN8(wa24,wa25,wa26,wa27,wa28,wa29,wa30,wa31)
    PIN8(wb0,wb1,wb2,wb3,wb4,wb5,wb6,wb7)
    PIN8(wb8,wb9,wb10,wb11,wb12,wb13,wb14,wb15)
    PIN8(wb16,wb17,wb18,wb19,wb20,wb21,wb22,wb23)
    PIN8(wb24,wb25,wb26,wb27,wb28,wb29,wb30,wb31)
#undef PIN8

    const int gc = m * 128 + tid;            // epilogue col (tid<128)

    // poller mapping (tid>=128): one u32 word of one peer
    const int q    = tid - 128;              // 0..383
    const int pp   = q >> 7;                 // 0..2
    const int pm   = pp + (pp >= m ? 1 : 0); // peer member
    const int pcol = pm * 128 + (q & 127);

    // zero f16 h
    hbf[tid] = 0;

    // fp32 h_old carried in registers (epilogue threads only)
    float hreg = 0.f;

    // prefetch t=0 xin(+b_rec)/noise
    float xin_pf = 0.f, noi_pf = 0.f;
    if (tid < 128) {
        xin_pf = rnn[(size_t)g * NH + gc];
        noi_pf = noise[(size_t)g * NH + gc];
    }
    __syncthreads();

    int alive  = 1;
    int budget = 1 << 16;   // launch-global spin budget (hang-proof)

    for (int t = 0; t < T; ++t) {
        // ---- dot: cols {l, l+64}, k in [64w,64w+64), f16 LDS + fdot2 ----
        float aA0 = 0.f, aA1 = 0.f, aB0 = 0.f, aB1 = 0.f;
        {
            const uint4* hp = (const uint4*)&hbf[w * 64];  // 8 x (8 f16)
#define DOTB(N, A0, A1, A2, A3) { const uint4 u_ = hp[N]; \
            aA0 = dot2(wa##A0, u_.x, aA0); aA1 = dot2(wa##A1, u_.y, aA1); \
            aA0 = dot2(wa##A2, u_.z, aA0); aA1 = dot2(wa##A3, u_.w, aA1); \
            aB0 = dot2(wb##A0, u_.x, aB0); aB1 = dot2(wb##A1, u_.y, aB1); \
            aB0 = dot2(wb##A2, u_.z, aB0); aB1 = dot2(wb##A3, u_.w, aB1); }
            DOTB(0,  0,  1,  2,  3)
            DOTB(1,  4,  5,  6,  7)
            DOTB(2,  8,  9, 10, 11)
            DOTB(3, 12, 13, 14, 15)
            DOTB(4, 16, 17, 18, 19)
            DOTB(5, 20, 21, 22, 23)
            DOTB(6, 24, 25, 26, 27)
            DOTB(7, 28, 29, 30, 31)
#undef DOTB
        }
        pr[w][l]      = aA0 + aA1;
        pr[w][l + 64] = aB0 + aB1;
        __syncthreads();

        const uint32_t want = (uint32_t)(t + 1);
        uint32_t* slot = ex + (size_t)(t & 1) * NB * NH;

        if (tid < 128) {
            // ---- epilogue: reduce 8 chunk-partials, update, publish ----
            float sum = 0.f;
            #pragma unroll
            for (int k = 0; k < 8; ++k) sum += pr[k][tid];
            const float hn = fmaxf(xin_pf + sum, 0.f);     // b_rec folded in xin
            const float nw = (1.f - ALPHA) * hreg + ALPHA * hn + NSC * noi_pf;
            hreg = nw;
            const uint32_t pk = pack_h(nw, want);
            (void)__hip_atomic_exchange(&slot[(size_t)g * NH + gc], pk,
                                        __ATOMIC_RELAXED, __HIP_MEMORY_SCOPE_AGENT);
            hbf[gc] = (unsigned short)(pk >> 16);          // own col, same rounding
            rnn[((size_t)t * NB + g) * NH + gc] = nw;
            const int tn = (t + 1 < T) ? (t + 1) : t;
            xin_pf = rnn[((size_t)tn * NB + g) * NH + gc];
            noi_pf = noise[((size_t)tn * NB + g) * NH + gc];
        } else {
            // ---- gather: poll one peer word via RMW ----
            uint32_t v;
            if (alive) {
                for (;;) {
                    v = __hip_atomic_fetch_or(&slot[(size_t)g * NH + pcol], 0u,
                                              __ATOMIC_RELAXED, __HIP_MEMORY_SCOPE_AGENT);
                    if ((v & 0xFFFFu) == (want & 0xFFFFu)) break;
                    __builtin_amdgcn_s_sleep(1);
                    if (--budget < 0) { alive = 0; break; }   // fail loudly
                }
            } else {
                v = __hip_atomic_fetch_or(&slot[(size_t)g * NH + pcol], 0u,
                                          __ATOMIC_RELAXED, __HIP_MEMORY_SCOPE_AGENT);
            }
            hbf[pcol] = (unsigned short)(v >> 16);
        }
        __syncthreads();
    }
}

// ---------------------------------------------------------------------------
extern "C" void kernel_launch(void* const* d_in, const int* in_sizes, int n_in,
                              void* d_out, int out_size, void* d_ws, size_t ws_size,
                              hipStream_t stream)
{
    (void)in_sizes; (void)n_in; (void)out_size; (void)ws_size;
    const float* x     = (const float*)d_in[0];
    const float* noise = (const float*)d_in[1];
    const float* W_in  = (const float*)d_in[2];
    const float* W_rec = (const float*)d_in[3];
    const float* b_rec = (const float*)d_in[4];
    const float* W_out = (const float*)d_in[5];
    const float* b_out = (const float*)d_in[6];

    float* out = (float*)d_out;                       // [T*B][O]
    float* rnn = out + (size_t)T * NB * NO;           // [T*B][H] (second output)

    uint32_t* ex = (uint32_t*)d_ws;                   // [2][B][H] = 256 KB

    // clear exchange tags (replay-deterministic; tag 0 never polled-for)
    hipMemsetAsync(ex, 0, (size_t)2 * NB * NH * sizeof(uint32_t), stream);

    // xin = x @ W_in^T + b_rec  -> written into rnn region (in-place consumed)
    hipLaunchKernelGGL(k_gemm_nt_bias, dim3((T * NB) / 64, NH / 64), dim3(256), 0, stream,
                       x, W_in, b_rec, rnn, T * NB, NH, NI);

    // sequential recurrence: 256 WGs, pinned-occupancy W-resident, fdot2
    hipLaunchKernelGGL(k_rnn, dim3(256), dim3(512), 0, stream,
                       W_rec, noise, rnn, ex);

    // output = rnn @ W_out^T + b_out
    hipLaunchKernelGGL(k_gemm_nt_bias, dim3((T * NB) / 64, NO / 64), dim3(256), 0, stream,
                       rnn, W_out, b_out, out, T * NB, NO, NH);
}